// Round 10
// baseline (298.187 us; speedup 1.0000x reference)
//
#include <hip/hip_runtime.h>
#include <stdint.h>

#define WINDOW 2048
#define EMBED  1024
#define BATCH  8
#define MTOT   (BATCH*WINDOW)   // 16384 rows total

typedef unsigned short u16;
typedef __bf16 bf16x8 __attribute__((ext_vector_type(8)));
typedef float  f32x4  __attribute__((ext_vector_type(4)));

#define BK 64
#define KSCALE 0.04508422717564447f   /* log2(e)/32 folded into stored K */

// ---- 256x256 tile, 8 waves (2M x 4N -> 128x64/wave), kk-split halves ----
#define BM2 256
#define BN2 256
#define HALF2 8192    // kk-half: 256r x 32c (16 KiB); 8 halves = 128 KiB

#define WAITVM4 asm volatile("s_waitcnt vmcnt(4)" ::: "memory")
#define WAITVM2 asm volatile("s_waitcnt vmcnt(2)" ::: "memory")
#define WAITVM0 asm volatile("s_waitcnt vmcnt(0)" ::: "memory")
#define SBAR    __builtin_amdgcn_s_barrier()

__device__ __forceinline__ u16 f2bf(float f) {
  union { float f; unsigned u; } a; a.f = f;
  unsigned r = a.u + 0x7FFF + ((a.u >> 16) & 1);   // RNE
  return (u16)(r >> 16);
}
__device__ __forceinline__ float bf2f(u16 u) {
  union { unsigned u; float f; } a; a.u = ((unsigned)u) << 16;
  return a.f;
}

__device__ __forceinline__ void gload16(const u16* g, u16* l) {
  __builtin_amdgcn_global_load_lds(
      (const __attribute__((address_space(1))) unsigned int*)g,
      (__attribute__((address_space(3))) unsigned int*)l, 16, 0, 0);
}

// Swizzle (rule #21): LDS dest LINEAR slot f = r*4 + c; global SOURCE chunk is
// c ^ ((r>>1)&3) (involution) so a read at slot hi^((r>>1)&3) sees logical
// chunk hi.  ds_read_b128 lands 2-way bank-aliased only (free, m136).

// ====== 256x256 core, m201 cadence: 4 phases/K-tile, 16 MFMA between two
// barriers per phase; ds_reads for the NEXT phase + 1 staging unit issued
// between BAR_close and the next BAR_open (latency hides in barrier drain).
// Counted vmcnt(2) only at ph1/ph3 (never 0 mid-loop). ======
__device__ __forceinline__ void gemm256(
    const u16* __restrict__ A, int lda,
    const u16* __restrict__ B, int ldb,
    int nt, u16* lds, f32x4 acc[8][4])
{
  const int tid  = threadIdx.x;
  const int lane = tid & 63;
  const int wid  = tid >> 6;
  const int wm   = (wid >> 2) * 128;
  const int wn   = (wid & 3) * 64;
  const int lrow = lane & 15;
  const int hi   = lane >> 4;
  u16* dA = lds;
  u16* dB = lds + 4 * HALF2;

  int aoff[8], boff[4];
  #pragma unroll
  for (int mi = 0; mi < 8; ++mi) {
    int r = wm + mi * 16 + lrow;
    aoff[mi] = r * 32 + ((hi ^ ((r >> 1) & 3)) << 3);
  }
  #pragma unroll
  for (int ni = 0; ni < 4; ++ni) {
    int r = wn + ni * 16 + lrow;
    boff[ni] = r * 32 + ((hi ^ ((r >> 1) & 3)) << 3);
  }

  const int f0 = tid, f1 = 512 + tid;
  const int r0 = f0 >> 2, r1 = f1 >> 2;
  const int c0 = (((f0 & 3) ^ ((r0 >> 1) & 3)) << 3);
  const int c1 = (((f1 & 3) ^ ((r1 >> 1) & 3)) << 3);
  const u16* pA0 = A + (size_t)r0 * lda + c0;
  const u16* pA1 = A + (size_t)r1 * lda + c1;
  const u16* pB0 = B + (size_t)r0 * ldb + c0;
  const u16* pB1 = B + (size_t)r1 * ldb + c1;
  const int d0 = f0 * 8, d1 = f1 * 8;

  // prologue: stage tile 0 (units: A.kk0, B.kk0, A.kk1, B.kk1 = 8 loads)
  gload16(pA0,      dA + d0);         gload16(pA1,      dA + d1);
  gload16(pB0,      dB + d0);         gload16(pB1,      dB + d1);
  gload16(pA0 + 32, dA + HALF2 + d0); gload16(pA1 + 32, dA + HALF2 + d1);
  gload16(pB0 + 32, dB + HALF2 + d0); gload16(pB1 + 32, dB + HALF2 + d1);
  pA0 += BK; pA1 += BK; pB0 += BK; pB1 += BK;
  WAITVM4;             // kk0 units landed; kk1 units (4 loads) stay in flight
  SBAR;

  bf16x8 av[4], bv[4];
  // initial fragments: ph0 of tile 0 (kk0, m-half 0) + bv(kk0)
  #pragma unroll
  for (int mi = 0; mi < 4; ++mi) av[mi] = *(const bf16x8*)(dA + aoff[mi]);
  #pragma unroll
  for (int ni = 0; ni < 4; ++ni) bv[ni] = *(const bf16x8*)(dB + boff[ni]);

  for (int t = 0; t < nt; ++t) {
    const int cb = (t & 1) * 2;
    const int nb = ((t + 1) & 1) * 2;
    u16* LA0 = dA + cb * HALF2;  u16* LA1 = LA0 + HALF2;
    u16* LB0 = dB + cb * HALF2;  u16* LB1 = LB0 + HALF2;
    u16* NA0 = dA + nb * HALF2;  u16* NB0 = dB + nb * HALF2;
    const bool s = (t + 1) < nt;

    // ===== ph0: MFMA (kk0, mh0) =====
    SBAR;
    __builtin_amdgcn_s_setprio(1);
    #pragma unroll
    for (int mi = 0; mi < 4; ++mi)
      #pragma unroll
      for (int ni = 0; ni < 4; ++ni)
        acc[mi][ni] = __builtin_amdgcn_mfma_f32_16x16x32_bf16(av[mi], bv[ni], acc[mi][ni], 0, 0, 0);
    __builtin_amdgcn_s_setprio(0);
    SBAR;
    #pragma unroll
    for (int mi = 0; mi < 4; ++mi) av[mi] = *(const bf16x8*)(LA0 + aoff[4 + mi]);  // ph1 frags
    if (s) { gload16(pA0, NA0 + d0); gload16(pA1, NA0 + d1); }                     // U(A,kk0,t+1)

    // ===== ph1: MFMA (kk0, mh1) =====
    SBAR;
    __builtin_amdgcn_s_setprio(1);
    #pragma unroll
    for (int mi = 0; mi < 4; ++mi)
      #pragma unroll
      for (int ni = 0; ni < 4; ++ni)
        acc[4 + mi][ni] = __builtin_amdgcn_mfma_f32_16x16x32_bf16(av[mi], bv[ni], acc[4 + mi][ni], 0, 0, 0);
    __builtin_amdgcn_s_setprio(0);
    if (s) { WAITVM2; } else { WAITVM0; }   // kk1(t) units landed (oldest 2 of 3)
    SBAR;
    #pragma unroll
    for (int mi = 0; mi < 4; ++mi) av[mi] = *(const bf16x8*)(LA1 + aoff[mi]);      // ph2 frags
    #pragma unroll
    for (int ni = 0; ni < 4; ++ni) bv[ni] = *(const bf16x8*)(LB1 + boff[ni]);
    if (s) { gload16(pB0, NB0 + d0); gload16(pB1, NB0 + d1); }                     // U(B,kk0,t+1)

    // ===== ph2: MFMA (kk1, mh0) =====
    SBAR;
    __builtin_amdgcn_s_setprio(1);
    #pragma unroll
    for (int mi = 0; mi < 4; ++mi)
      #pragma unroll
      for (int ni = 0; ni < 4; ++ni)
        acc[mi][ni] = __builtin_amdgcn_mfma_f32_16x16x32_bf16(av[mi], bv[ni], acc[mi][ni], 0, 0, 0);
    __builtin_amdgcn_s_setprio(0);
    SBAR;
    #pragma unroll
    for (int mi = 0; mi < 4; ++mi) av[mi] = *(const bf16x8*)(LA1 + aoff[4 + mi]);  // ph3 frags
    if (s) { gload16(pA0 + 32, NA0 + HALF2 + d0); gload16(pA1 + 32, NA0 + HALF2 + d1); } // U(A,kk1,t+1)

    // ===== ph3: MFMA (kk1, mh1) =====
    SBAR;
    __builtin_amdgcn_s_setprio(1);
    #pragma unroll
    for (int mi = 0; mi < 4; ++mi)
      #pragma unroll
      for (int ni = 0; ni < 4; ++ni)
        acc[4 + mi][ni] = __builtin_amdgcn_mfma_f32_16x16x32_bf16(av[mi], bv[ni], acc[4 + mi][ni], 0, 0, 0);
    __builtin_amdgcn_s_setprio(0);
    if (s) { WAITVM2; }                     // kk0(t+1) units landed
    SBAR;
    if (s) {
      #pragma unroll
      for (int mi = 0; mi < 4; ++mi) av[mi] = *(const bf16x8*)(NA0 + aoff[mi]);    // next ph0 frags
      #pragma unroll
      for (int ni = 0; ni < 4; ++ni) bv[ni] = *(const bf16x8*)(NB0 + boff[ni]);
      gload16(pB0 + 32, NB0 + HALF2 + d0); gload16(pB1 + 32, NB0 + HALF2 + d1);    // U(B,kk1,t+1)
      pA0 += BK; pA1 += BK; pB0 += BK; pB1 += BK;
    }
  }
}

// ---------------- fp32 -> bf16 convert (vectorized) ----------------
__global__ __launch_bounds__(256) void k_cvt(const float* __restrict__ in,
                                             u16* __restrict__ out, int n) {
  int i = (blockIdx.x * 256 + threadIdx.x) * 4;
  if (i >= n) return;
  float4 v = *(const float4*)(in + i);
  ushort4 o;
  o.x = f2bf(v.x); o.y = f2bf(v.y); o.z = f2bf(v.z); o.w = f2bf(v.w);
  *(ushort4*)(out + i) = o;
}

// 3 weight matrices in one launch (blockIdx.y selects)
__global__ __launch_bounds__(256) void k_cvtw(const float* __restrict__ w0,
                                              const float* __restrict__ w1,
                                              const float* __restrict__ w2,
                                              u16* __restrict__ out) {
  const float* in = (blockIdx.y == 0) ? w0 : (blockIdx.y == 1) ? w1 : w2;
  u16* o = out + (size_t)blockIdx.y * EMBED * EMBED;
  int i = (blockIdx.x * 256 + threadIdx.x) * 4;
  float4 v = *(const float4*)(in + i);
  ushort4 r;
  r.x = f2bf(v.x); r.y = f2bf(v.y); r.z = f2bf(v.z); r.w = f2bf(v.w);
  *(ushort4*)(o + i) = r;
}

// ---------------- QKV projection: C = X * W^T + b ----------------
// 1D grid, XCD-aware decode: xcd = bid&7 owns m-tiles [8*xcd, 8*xcd+7].
__global__ __launch_bounds__(512, 2) void k_qkv(
    const u16* __restrict__ Xb, const u16* __restrict__ Wb,
    const float* __restrict__ bq, const float* __restrict__ bk, const float* __restrict__ bv,
    u16* __restrict__ Q, u16* __restrict__ Ks, u16* __restrict__ V)
{
  __shared__ u16 lds[8 * HALF2];
  const int bid   = blockIdx.x;
  const int xcd   = bid & 7;
  const int g     = bid >> 3;        // 0..95
  const int mloc  = g & 7;           // m inner
  const int combo = g >> 3;          // 0..11 = (y,z)
  const int m0 = (xcd * 8 + mloc) * BM2;
  const int n0 = (combo & 3) * BN2;
  const int z  = combo >> 2;
  const u16*   W    = Wb + (size_t)z * EMBED * EMBED;
  const float* bias = (z == 0) ? bq : (z == 1) ? bk : bv;
  u16* out          = (z == 0) ? Q  : (z == 1) ? Ks : V;
  const float scale = (z == 1) ? KSCALE : 1.0f;

  f32x4 acc[8][4];
  const f32x4 zz = {0.f,0.f,0.f,0.f};
  #pragma unroll
  for (int i = 0; i < 8; ++i) for (int j = 0; j < 4; ++j) acc[i][j] = zz;
  gemm256(Xb + (size_t)m0 * EMBED, EMBED, W + (size_t)n0 * EMBED, EMBED,
          EMBED / BK, lds, acc);

  const int lane = threadIdx.x & 63, wid = threadIdx.x >> 6;
  const int wm = (wid >> 2) * 128, wn = (wid & 3) * 64;
  const int lrow = lane & 15, hi = lane >> 4;
  #pragma unroll
  for (int mi = 0; mi < 8; ++mi)
    #pragma unroll
    for (int ni = 0; ni < 4; ++ni)
      #pragma unroll
      for (int rr = 0; rr < 4; ++rr) {
        int gm = m0 + wm + mi * 16 + hi * 4 + rr;
        int gn = n0 + wn + ni * 16 + lrow;
        out[(size_t)gm * EMBED + gn] = f2bf((acc[mi][ni][rr] + bias[gn]) * scale);
      }
}

// ---------------- S = Q*K^T, P = exp2(S) masked, D[j] += colsum ----------------
__global__ __launch_bounds__(512, 2) void k_spd(
    const u16* __restrict__ Q, const u16* __restrict__ Ks,
    u16* __restrict__ P, float* __restrict__ D)
{
  const int i0 = blockIdx.x * BM2;
  const int j0 = blockIdx.y * BN2;
  if (j0 > i0) return;                       // fully-masked tile: P never read there
  const int b  = blockIdx.z;
  __shared__ u16 lds[8 * HALF2];
  const u16* A = Q  + (size_t)b * WINDOW * EMBED + (size_t)i0 * EMBED;
  const u16* B = Ks + (size_t)b * WINDOW * EMBED + (size_t)j0 * EMBED;
  f32x4 acc[8][4];
  const f32x4 zz = {0.f,0.f,0.f,0.f};
  #pragma unroll
  for (int i = 0; i < 8; ++i) for (int j = 0; j < 4; ++j) acc[i][j] = zz;
  gemm256(A, EMBED, B, EMBED, EMBED / BK, lds, acc);

  u16* Pb   = P + (size_t)b * WINDOW * WINDOW;
  float* Db = D + (size_t)b * WINDOW;
  const int lane = threadIdx.x & 63, wid = threadIdx.x >> 6;
  const int wm = (wid >> 2) * 128, wn = (wid & 3) * 64;
  const int lrow = lane & 15, hi = lane >> 4;
  #pragma unroll
  for (int ni = 0; ni < 4; ++ni) {
    int gj = j0 + wn + ni * 16 + lrow;
    float csum = 0.f;
    #pragma unroll
    for (int mi = 0; mi < 8; ++mi)
      #pragma unroll
      for (int rr = 0; rr < 4; ++rr) {
        int gi = i0 + wm + mi * 16 + hi * 4 + rr;
        float p = (gi >= gj) ? exp2f(acc[mi][ni][rr]) : 0.0f;  // S pre-scaled by log2e/32
        Pb[(size_t)gi * WINDOW + gj] = f2bf(p);
        csum += p;
      }
    csum += __shfl_xor(csum, 16, 64);
    csum += __shfl_xor(csum, 32, 64);
    if (hi == 0) atomicAdd(&Db[gj], csum);
  }
}

// ---------------- Vdt[e][j] = V[j][e] / D[j]  (transpose + scale) ----------------
__global__ __launch_bounds__(256) void k_vdt(
    const u16* __restrict__ V, const float* __restrict__ D, u16* __restrict__ Vdt)
{
  __shared__ u16 tile[64][68];
  const int j0 = blockIdx.x * 64, e0 = blockIdx.y * 64, b = blockIdx.z;
  const u16* Vb = V   + (size_t)b * WINDOW * EMBED;
  u16* Tb       = Vdt + (size_t)b * EMBED * WINDOW;
  const float* Db = D + (size_t)b * WINDOW;
  const int t = threadIdx.x;
  const int rr = t >> 4;
  const int cc = (t & 15) * 4;
  #pragma unroll
  for (int p = 0; p < 4; ++p) {
    int r = p * 16 + rr;
    *(uint2*)&tile[r][cc] = *(const uint2*)(Vb + (size_t)(j0 + r) * EMBED + e0 + cc);
  }
  __syncthreads();
  #pragma unroll
  for (int p = 0; p < 4; ++p) {
    int er = p * 16 + rr;
    ushort4 o;
    o.x = f2bf(bf2f(tile[cc + 0][er]) / Db[j0 + cc + 0]);
    o.y = f2bf(bf2f(tile[cc + 1][er]) / Db[j0 + cc + 1]);
    o.z = f2bf(bf2f(tile[cc + 2][er]) / Db[j0 + cc + 2]);
    o.w = f2bf(bf2f(tile[cc + 3][er]) / Db[j0 + cc + 3]);
    *(ushort4*)(Tb + (size_t)(e0 + er) * WINDOW + j0 + cc) = o;
  }
}

// ---------------- O = P * Vdt^T  (causal K-length), fp32 out ----------------
__global__ __launch_bounds__(512, 2) void k_out(
    const u16* __restrict__ P, const u16* __restrict__ Vdt, float* __restrict__ O)
{
  __shared__ u16 lds[8 * HALF2];
  const int i0 = ((int)gridDim.x - 1 - (int)blockIdx.x) * BM2;  // longest first
  const int e0 = blockIdx.y * BN2;
  const int b  = blockIdx.z;
  const u16* A = P   + (size_t)b * WINDOW * WINDOW + (size_t)i0 * WINDOW;
  const u16* B = Vdt + (size_t)b * EMBED * WINDOW  + (size_t)e0 * WINDOW;
  f32x4 acc[8][4];
  const f32x4 zz = {0.f,0.f,0.f,0.f};
  #pragma unroll
  for (int i = 0; i < 8; ++i) for (int j = 0; j < 4; ++j) acc[i][j] = zz;
  gemm256(A, WINDOW, B, WINDOW, (i0 + BM2) / BK, lds, acc);  // j <= i only

  float* Ob = O + (size_t)b * WINDOW * EMBED;
  const int lane = threadIdx.x & 63, wid = threadIdx.x >> 6;
  const int wm = (wid >> 2) * 128, wn = (wid & 3) * 64;
  const int lrow = lane & 15, hi = lane >> 4;
  #pragma unroll
  for (int mi = 0; mi < 8; ++mi)
    #pragma unroll
    for (int ni = 0; ni < 4; ++ni)
      #pragma unroll
      for (int rr = 0; rr < 4; ++rr) {
        int gi = i0 + wm + mi * 16 + hi * 4 + rr;
        int ge = e0 + wn + ni * 16 + lrow;
        Ob[(size_t)gi * EMBED + ge] = acc[mi][ni][rr];
      }
}

extern "C" void kernel_launch(void* const* d_in, const int* in_sizes, int n_in,
                              void* d_out, int out_size, void* d_ws, size_t ws_size,
                              hipStream_t stream) {
  const float* X  = (const float*)d_in[0];
  const float* Wq = (const float*)d_in[1];
  const float* bq = (const float*)d_in[2];
  const float* Wk = (const float*)d_in[3];
  const float* bk = (const float*)d_in[4];
  const float* Wv = (const float*)d_in[5];
  const float* bv = (const float*)d_in[6];
  float* O = (float*)d_out;

  char* ws = (char*)d_ws;
  size_t off = 0;
  auto alloc = [&](size_t bytes) -> void* {
    void* p = ws + off; off += (bytes + 255) & ~(size_t)255; return p;
  };
  u16*  Xb  = (u16*)alloc((size_t)MTOT * EMBED * 2);
  u16*  Wb  = (u16*)alloc((size_t)3 * EMBED * EMBED * 2);
  u16*  Qb  = (u16*)alloc((size_t)MTOT * EMBED * 2);
  u16*  Kb  = (u16*)alloc((size_t)MTOT * EMBED * 2);          // pre-scaled by log2e/32
  u16*  Vb  = (u16*)alloc((size_t)MTOT * EMBED * 2);
  u16*  Vdt = (u16*)alloc((size_t)BATCH * EMBED * WINDOW * 2);
  u16*  P   = (u16*)alloc((size_t)BATCH * WINDOW * WINDOW * 2);
  float* D  = (float*)alloc((size_t)MTOT * 4);
  (void)ws_size; (void)in_sizes; (void)n_in; (void)out_size;

  // 0) fp32 -> bf16 converts (X; then all 3 W's in one launch)
  k_cvt<<<dim3((MTOT * EMBED / 4 + 255) / 256), 256, 0, stream>>>(X, Xb, MTOT * EMBED);
  k_cvtw<<<dim3(EMBED * EMBED / 4 / 256, 3), 256, 0, stream>>>(Wq, Wk, Wv, Wb);

  // 1) Q/K/V projections (768 blocks, XCD-aware 1D decode)
  k_qkv<<<dim3(768), 512, 0, stream>>>(Xb, Wb, bq, bk, bv, Qb, Kb, Vb);

  // 2) P = exp(QK^T/sqrt(E)) masked; D[j] = column sums
  (void)hipMemsetAsync(D, 0, (size_t)MTOT * 4, stream);
  k_spd<<<dim3(WINDOW / BM2, WINDOW / BN2, BATCH), 512, 0, stream>>>(Qb, Kb, P, D);

  // 3) Vdt[e][j] = V[j][e] / D[j]
  k_vdt<<<dim3(WINDOW / 64, EMBED / 64, BATCH), 256, 0, stream>>>(Vb, D, Vdt);

  // 4) O = P * Vdt^T (causal K-length per row-tile, longest first)
  k_out<<<dim3(WINDOW / BM2, EMBED / BN2, BATCH), 512, 0, stream>>>(P, Vdt, O);
}

// Round 11
// 296.828 us; speedup vs baseline: 1.0046x; 1.0046x over previous
//
#include <hip/hip_runtime.h>
#include <stdint.h>

#define WINDOW 2048
#define EMBED  1024
#define BATCH  8
#define MTOT   (BATCH*WINDOW)   // 16384 rows total

typedef unsigned short u16;
typedef __bf16 bf16x8 __attribute__((ext_vector_type(8)));
typedef float  f32x4  __attribute__((ext_vector_type(4)));

#define BK 64
#define KSCALE 0.04508422717564447f   /* log2(e)/32 folded into stored K */

// ---- 256x256 tile, 8 waves (2M x 4N -> 128x64/wave), kk-split halves ----
#define BM2 256
#define BN2 256
#define HALF2 8192    // kk-half: 256r x 32c (16 KiB); 8 halves = 128 KiB
#define PLD  260      // padded LDS row (u16) for the P-bounce epilogue

#define WAITVM4 asm volatile("s_waitcnt vmcnt(4)" ::: "memory")
#define WAITVM0 asm volatile("s_waitcnt vmcnt(0)" ::: "memory")
#define SBAR    __builtin_amdgcn_s_barrier()

__device__ __forceinline__ u16 f2bf(float f) {
  union { float f; unsigned u; } a; a.f = f;
  unsigned r = a.u + 0x7FFF + ((a.u >> 16) & 1);   // RNE
  return (u16)(r >> 16);
}
__device__ __forceinline__ float bf2f(u16 u) {
  union { unsigned u; float f; } a; a.u = ((unsigned)u) << 16;
  return a.f;
}

__device__ __forceinline__ void gload16(const u16* g, u16* l) {
  __builtin_amdgcn_global_load_lds(
      (const __attribute__((address_space(1))) unsigned int*)g,
      (__attribute__((address_space(3))) unsigned int*)l, 16, 0, 0);
}

// Swizzle (rule #21): LDS dest LINEAR slot f = r*4 + c; global SOURCE chunk is
// c ^ ((r>>1)&3) (involution) so a read at slot hi^((r>>1)&3) sees logical
// chunk hi.  ds_read_b128 lands 2-way bank-aliased only (free, m136).

// ============ 256x256 core: acc[8][4], 2 phases/K-tile (32 MFMA each) ============
__device__ __forceinline__ void gemm256(
    const u16* __restrict__ A, int lda,
    const u16* __restrict__ B, int ldb,
    int nt, u16* lds, f32x4 acc[8][4])
{
  const int tid  = threadIdx.x;
  const int lane = tid & 63;
  const int wid  = tid >> 6;
  const int wm   = (wid >> 2) * 128;
  const int wn   = (wid & 3) * 64;
  const int lrow = lane & 15;
  const int hi   = lane >> 4;
  u16* dA = lds;
  u16* dB = lds + 4 * HALF2;

  int aoff[8], boff[4];
  #pragma unroll
  for (int mi = 0; mi < 8; ++mi) {
    int r = wm + mi * 16 + lrow;
    aoff[mi] = r * 32 + ((hi ^ ((r >> 1) & 3)) << 3);
  }
  #pragma unroll
  for (int ni = 0; ni < 4; ++ni) {
    int r = wn + ni * 16 + lrow;
    boff[ni] = r * 32 + ((hi ^ ((r >> 1) & 3)) << 3);
  }

  const int f0 = tid, f1 = 512 + tid;
  const int r0 = f0 >> 2, r1 = f1 >> 2;
  const int c0 = (((f0 & 3) ^ ((r0 >> 1) & 3)) << 3);
  const int c1 = (((f1 & 3) ^ ((r1 >> 1) & 3)) << 3);
  const u16* pA0 = A + (size_t)r0 * lda + c0;
  const u16* pA1 = A + (size_t)r1 * lda + c1;
  const u16* pB0 = B + (size_t)r0 * ldb + c0;
  const u16* pB1 = B + (size_t)r1 * ldb + c1;
  const int d0 = f0 * 8, d1 = f1 * 8;

  gload16(pA0,      dA + d0);         gload16(pA1,      dA + d1);
  gload16(pB0,      dB + d0);         gload16(pB1,      dB + d1);
  gload16(pA0 + 32, dA + HALF2 + d0); gload16(pA1 + 32, dA + HALF2 + d1);
  gload16(pB0 + 32, dB + HALF2 + d0); gload16(pB1 + 32, dB + HALF2 + d1);
  pA0 += BK; pA1 += BK; pB0 += BK; pB1 += BK;
  WAITVM4;
  SBAR;

  for (int t = 0; t < nt; ++t) {
    const int cb = (t & 1) * 2;
    const int nb = ((t + 1) & 1) * 2;
    u16* LA0 = dA + cb * HALF2;  u16* LA1 = LA0 + HALF2;
    u16* LB0 = dB + cb * HALF2;  u16* LB1 = LB0 + HALF2;
    const bool s = (t + 1) < nt;
    bf16x8 av[8], bv[4];

    #pragma unroll
    for (int mi = 0; mi < 8; ++mi) av[mi] = *(const bf16x8*)(LA0 + aoff[mi]);
    #pragma unroll
    for (int ni = 0; ni < 4; ++ni) bv[ni] = *(const bf16x8*)(LB0 + boff[ni]);
    if (s) {
      gload16(pA0, dA + nb * HALF2 + d0); gload16(pA1, dA + nb * HALF2 + d1);
      gload16(pB0, dB + nb * HALF2 + d0); gload16(pB1, dB + nb * HALF2 + d1);
    }
    __builtin_amdgcn_s_setprio(1);
    #pragma unroll
    for (int mi = 0; mi < 8; ++mi)
      #pragma unroll
      for (int ni = 0; ni < 4; ++ni)
        acc[mi][ni] = __builtin_amdgcn_mfma_f32_16x16x32_bf16(av[mi], bv[ni], acc[mi][ni], 0, 0, 0);
    __builtin_amdgcn_s_setprio(0);
    if (s) { WAITVM4; } else { WAITVM0; }
    SBAR;

    #pragma unroll
    for (int mi = 0; mi < 8; ++mi) av[mi] = *(const bf16x8*)(LA1 + aoff[mi]);
    #pragma unroll
    for (int ni = 0; ni < 4; ++ni) bv[ni] = *(const bf16x8*)(LB1 + boff[ni]);
    if (s) {
      gload16(pA0 + 32, dA + nb * HALF2 + HALF2 + d0); gload16(pA1 + 32, dA + nb * HALF2 + HALF2 + d1);
      gload16(pB0 + 32, dB + nb * HALF2 + HALF2 + d0); gload16(pB1 + 32, dB + nb * HALF2 + HALF2 + d1);
      pA0 += BK; pA1 += BK; pB0 += BK; pB1 += BK;
    }
    __builtin_amdgcn_s_setprio(1);
    #pragma unroll
    for (int mi = 0; mi < 8; ++mi)
      #pragma unroll
      for (int ni = 0; ni < 4; ++ni)
        acc[mi][ni] = __builtin_amdgcn_mfma_f32_16x16x32_bf16(av[mi], bv[ni], acc[mi][ni], 0, 0, 0);
    __builtin_amdgcn_s_setprio(0);
    if (s) { WAITVM4; }
    SBAR;
  }
}

// ---------------- fp32 -> bf16 convert (vectorized) ----------------
__global__ __launch_bounds__(256) void k_cvt(const float* __restrict__ in,
                                             u16* __restrict__ out, int n) {
  int i = (blockIdx.x * 256 + threadIdx.x) * 4;
  if (i >= n) return;
  float4 v = *(const float4*)(in + i);
  ushort4 o;
  o.x = f2bf(v.x); o.y = f2bf(v.y); o.z = f2bf(v.z); o.w = f2bf(v.w);
  *(ushort4*)(out + i) = o;
}

// 3 weight matrices in one launch (blockIdx.y selects)
__global__ __launch_bounds__(256) void k_cvtw(const float* __restrict__ w0,
                                              const float* __restrict__ w1,
                                              const float* __restrict__ w2,
                                              u16* __restrict__ out) {
  const float* in = (blockIdx.y == 0) ? w0 : (blockIdx.y == 1) ? w1 : w2;
  u16* o = out + (size_t)blockIdx.y * EMBED * EMBED;
  int i = (blockIdx.x * 256 + threadIdx.x) * 4;
  float4 v = *(const float4*)(in + i);
  ushort4 r;
  r.x = f2bf(v.x); r.y = f2bf(v.y); r.z = f2bf(v.z); r.w = f2bf(v.w);
  *(ushort4*)(o + i) = r;
}

// ---------------- QKV projection: C = X * W^T + b ----------------
__global__ __launch_bounds__(512, 2) void k_qkv(
    const u16* __restrict__ Xb, const u16* __restrict__ Wb,
    const float* __restrict__ bq, const float* __restrict__ bk, const float* __restrict__ bv,
    u16* __restrict__ Q, u16* __restrict__ Ks, u16* __restrict__ V)
{
  __shared__ u16 lds[8 * HALF2];
  const int m0 = blockIdx.x * BM2;
  const int n0 = blockIdx.y * BN2;
  const int z  = blockIdx.z;
  const u16*   W    = Wb + (size_t)z * EMBED * EMBED;
  const float* bias = (z == 0) ? bq : (z == 1) ? bk : bv;
  u16* out          = (z == 0) ? Q  : (z == 1) ? Ks : V;
  const float scale = (z == 1) ? KSCALE : 1.0f;

  f32x4 acc[8][4];
  const f32x4 zz = {0.f,0.f,0.f,0.f};
  #pragma unroll
  for (int i = 0; i < 8; ++i) for (int j = 0; j < 4; ++j) acc[i][j] = zz;
  gemm256(Xb + (size_t)m0 * EMBED, EMBED, W + (size_t)n0 * EMBED, EMBED,
          EMBED / BK, lds, acc);

  const int lane = threadIdx.x & 63, wid = threadIdx.x >> 6;
  const int wm = (wid >> 2) * 128, wn = (wid & 3) * 64;
  const int lrow = lane & 15, hi = lane >> 4;
  #pragma unroll
  for (int mi = 0; mi < 8; ++mi)
    #pragma unroll
    for (int ni = 0; ni < 4; ++ni)
      #pragma unroll
      for (int rr = 0; rr < 4; ++rr) {
        int gm = m0 + wm + mi * 16 + hi * 4 + rr;
        int gn = n0 + wn + ni * 16 + lrow;
        out[(size_t)gm * EMBED + gn] = f2bf((acc[mi][ni][rr] + bias[gn]) * scale);
      }
}

// -- S = Q*K^T, P = exp2(S) masked, D[j] += colsum; P staged via LDS bounce --
__global__ __launch_bounds__(512, 2) void k_spd(
    const u16* __restrict__ Q, const u16* __restrict__ Ks,
    u16* __restrict__ P, float* __restrict__ D)
{
  const int i0 = blockIdx.x * BM2;
  const int j0 = blockIdx.y * BN2;
  if (j0 > i0) return;                       // fully-masked tile: P never read there
  const int b  = blockIdx.z;
  __shared__ u16 lds[BM2 * PLD];             // 133120 B: gemm uses first 128 KiB
  const u16* A = Q  + (size_t)b * WINDOW * EMBED + (size_t)i0 * EMBED;
  const u16* B = Ks + (size_t)b * WINDOW * EMBED + (size_t)j0 * EMBED;
  f32x4 acc[8][4];
  const f32x4 zz = {0.f,0.f,0.f,0.f};
  #pragma unroll
  for (int i = 0; i < 8; ++i) for (int j = 0; j < 4; ++j) acc[i][j] = zz;
  gemm256(A, EMBED, B, EMBED, EMBED / BK, lds, acc);

  u16* Pb   = P + (size_t)b * WINDOW * WINDOW;
  float* Db = D + (size_t)b * WINDOW;
  const int tid  = threadIdx.x;
  const int lane = tid & 63, wid = tid >> 6;
  const int wm = (wid >> 2) * 128, wn = (wid & 3) * 64;
  const int lrow = lane & 15, hi = lane >> 4;

  // phase 1: P-tile -> LDS [256][PLD] (pad keeps writes <=2-way banked),
  //          column sums -> atomics (from registers, unchanged)
  #pragma unroll
  for (int ni = 0; ni < 4; ++ni) {
    int lj = wn + ni * 16 + lrow;           // local col
    float csum = 0.f;
    #pragma unroll
    for (int mi = 0; mi < 8; ++mi)
      #pragma unroll
      for (int rr = 0; rr < 4; ++rr) {
        int li = wm + mi * 16 + hi * 4 + rr;  // local row
        float p = ((i0 + li) >= (j0 + lj)) ? exp2f(acc[mi][ni][rr]) : 0.0f;
        lds[li * PLD + lj] = f2bf(p);
        csum += p;
      }
    csum += __shfl_xor(csum, 16, 64);
    csum += __shfl_xor(csum, 32, 64);
    if (hi == 0) atomicAdd(&Db[j0 + lj], csum);
  }
  __syncthreads();

  // phase 2: coalesced copy-out. 8192 16B-chunks; lanes 0..31 cover one full
  // 512B row contiguously -> 2 rows / wave-instruction, fully coalesced.
  #pragma unroll
  for (int it = 0; it < 16; ++it) {
    int f   = it * 512 + tid;
    int row = f >> 5;
    int c   = f & 31;
    bf16x8 v = *(const bf16x8*)(lds + row * PLD + c * 8);
    *(bf16x8*)(Pb + (size_t)(i0 + row) * WINDOW + j0 + c * 8) = v;
  }
}

// ---------------- Vdt[e][j] = V[j][e] / D[j]  (transpose + scale) ----------------
__global__ __launch_bounds__(256) void k_vdt(
    const u16* __restrict__ V, const float* __restrict__ D, u16* __restrict__ Vdt)
{
  __shared__ u16 tile[64][68];
  const int j0 = blockIdx.x * 64, e0 = blockIdx.y * 64, b = blockIdx.z;
  const u16* Vb = V   + (size_t)b * WINDOW * EMBED;
  u16* Tb       = Vdt + (size_t)b * EMBED * WINDOW;
  const float* Db = D + (size_t)b * WINDOW;
  const int t = threadIdx.x;
  const int rr = t >> 4;
  const int cc = (t & 15) * 4;
  #pragma unroll
  for (int p = 0; p < 4; ++p) {
    int r = p * 16 + rr;
    *(uint2*)&tile[r][cc] = *(const uint2*)(Vb + (size_t)(j0 + r) * EMBED + e0 + cc);
  }
  __syncthreads();
  #pragma unroll
  for (int p = 0; p < 4; ++p) {
    int er = p * 16 + rr;
    ushort4 o;
    o.x = f2bf(bf2f(tile[cc + 0][er]) / Db[j0 + cc + 0]);
    o.y = f2bf(bf2f(tile[cc + 1][er]) / Db[j0 + cc + 1]);
    o.z = f2bf(bf2f(tile[cc + 2][er]) / Db[j0 + cc + 2]);
    o.w = f2bf(bf2f(tile[cc + 3][er]) / Db[j0 + cc + 3]);
    *(ushort4*)(Tb + (size_t)(e0 + er) * WINDOW + j0 + cc) = o;
  }
}

// ---------------- O = P * Vdt^T  (causal K-length), fp32 out ----------------
__global__ __launch_bounds__(512, 2) void k_out(
    const u16* __restrict__ P, const u16* __restrict__ Vdt, float* __restrict__ O)
{
  __shared__ u16 lds[8 * HALF2];
  const int i0 = ((int)gridDim.x - 1 - (int)blockIdx.x) * BM2;  // longest first
  const int e0 = blockIdx.y * BN2;
  const int b  = blockIdx.z;
  const u16* A = P   + (size_t)b * WINDOW * WINDOW + (size_t)i0 * WINDOW;
  const u16* B = Vdt + (size_t)b * EMBED * WINDOW  + (size_t)e0 * WINDOW;
  f32x4 acc[8][4];
  const f32x4 zz = {0.f,0.f,0.f,0.f};
  #pragma unroll
  for (int i = 0; i < 8; ++i) for (int j = 0; j < 4; ++j) acc[i][j] = zz;
  gemm256(A, WINDOW, B, WINDOW, (i0 + BM2) / BK, lds, acc);  // j <= i only

  float* Ob = O + (size_t)b * WINDOW * EMBED;
  const int lane = threadIdx.x & 63, wid = threadIdx.x >> 6;
  const int wm = (wid >> 2) * 128, wn = (wid & 3) * 64;
  const int lrow = lane & 15, hi = lane >> 4;
  #pragma unroll
  for (int mi = 0; mi < 8; ++mi)
    #pragma unroll
    for (int ni = 0; ni < 4; ++ni)
      #pragma unroll
      for (int rr = 0; rr < 4; ++rr) {
        int gi = i0 + wm + mi * 16 + hi * 4 + rr;
        int ge = e0 + wn + ni * 16 + lrow;
        Ob[(size_t)gi * EMBED + ge] = acc[mi][ni][rr];
      }
}

extern "C" void kernel_launch(void* const* d_in, const int* in_sizes, int n_in,
                              void* d_out, int out_size, void* d_ws, size_t ws_size,
                              hipStream_t stream) {
  const float* X  = (const float*)d_in[0];
  const float* Wq = (const float*)d_in[1];
  const float* bq = (const float*)d_in[2];
  const float* Wk = (const float*)d_in[3];
  const float* bk = (const float*)d_in[4];
  const float* Wv = (const float*)d_in[5];
  const float* bv = (const float*)d_in[6];
  float* O = (float*)d_out;

  char* ws = (char*)d_ws;
  size_t off = 0;
  auto alloc = [&](size_t bytes) -> void* {
    void* p = ws + off; off += (bytes + 255) & ~(size_t)255; return p;
  };
  u16*  Xb  = (u16*)alloc((size_t)MTOT * EMBED * 2);
  u16*  Wb  = (u16*)alloc((size_t)3 * EMBED * EMBED * 2);
  u16*  Qb  = (u16*)alloc((size_t)MTOT * EMBED * 2);
  u16*  Kb  = (u16*)alloc((size_t)MTOT * EMBED * 2);          // pre-scaled by log2e/32
  u16*  Vb  = (u16*)alloc((size_t)MTOT * EMBED * 2);
  u16*  Vdt = (u16*)alloc((size_t)BATCH * EMBED * WINDOW * 2);
  u16*  P   = (u16*)alloc((size_t)BATCH * WINDOW * WINDOW * 2);
  float* D  = (float*)alloc((size_t)MTOT * 4);
  (void)ws_size; (void)in_sizes; (void)n_in; (void)out_size;

  // 0) fp32 -> bf16 converts (X; then all 3 W's in one launch)
  k_cvt<<<dim3((MTOT * EMBED / 4 + 255) / 256), 256, 0, stream>>>(X, Xb, MTOT * EMBED);
  k_cvtw<<<dim3(EMBED * EMBED / 4 / 256, 3), 256, 0, stream>>>(Wq, Wk, Wv, Wb);

  // 1) Q/K/V projections (768 blocks = 3 dispatch rounds)
  k_qkv<<<dim3(MTOT / BM2, EMBED / BN2, 3), 512, 0, stream>>>(Xb, Wb, bq, bk, bv, Qb, Kb, Vb);

  // 2) P = exp(QK^T/sqrt(E)) masked; D[j] = column sums
  (void)hipMemsetAsync(D, 0, (size_t)MTOT * 4, stream);
  k_spd<<<dim3(WINDOW / BM2, WINDOW / BN2, BATCH), 512, 0, stream>>>(Qb, Kb, P, D);

  // 3) Vdt[e][j] = V[j][e] / D[j]
  k_vdt<<<dim3(WINDOW / 64, EMBED / 64, BATCH), 256, 0, stream>>>(Vb, D, Vdt);

  // 4) O = P * Vdt^T (causal K-length per row-tile, longest first)
  k_out<<<dim3(WINDOW / BM2, EMBED / BN2, BATCH), 512, 0, stream>>>(P, Vdt, O);
}

// Round 12
// 278.778 us; speedup vs baseline: 1.0696x; 1.0647x over previous
//
#include <hip/hip_runtime.h>
#include <stdint.h>

#define WINDOW 2048
#define EMBED  1024
#define BATCH  8
#define MTOT   (BATCH*WINDOW)   // 16384 rows total

typedef unsigned short u16;
typedef __bf16 bf16x8 __attribute__((ext_vector_type(8)));
typedef float  f32x4  __attribute__((ext_vector_type(4)));

#define BK 64
#define KSCALE 0.04508422717564447f   /* log2(e)/32 folded into stored K */

// ---- 256x256 tile, 8 waves (2M x 4N -> 128x64/wave), kk-split halves ----
#define BM2 256
#define BN2 256
#define HALF2 8192    // kk-half: 256r x 32c (16 KiB); 8 halves = 128 KiB
#define PLD  260      // padded LDS row (u16) for the P-bounce epilogue

#define WAITVM4 asm volatile("s_waitcnt vmcnt(4)" ::: "memory")
#define WAITVM0 asm volatile("s_waitcnt vmcnt(0)" ::: "memory")
#define SBAR    __builtin_amdgcn_s_barrier()

__device__ __forceinline__ u16 f2bf(float f) {
  union { float f; unsigned u; } a; a.f = f;
  unsigned r = a.u + 0x7FFF + ((a.u >> 16) & 1);   // RNE
  return (u16)(r >> 16);
}
__device__ __forceinline__ float bf2f(u16 u) {
  union { unsigned u; float f; } a; a.u = ((unsigned)u) << 16;
  return a.f;
}

__device__ __forceinline__ void gload16(const u16* g, u16* l) {
  __builtin_amdgcn_global_load_lds(
      (const __attribute__((address_space(1))) unsigned int*)g,
      (__attribute__((address_space(3))) unsigned int*)l, 16, 0, 0);
}

// Swizzle (rule #21): LDS dest LINEAR slot f = r*4 + c; global SOURCE chunk is
// c ^ ((r>>1)&3) (involution) so a read at slot hi^((r>>1)&3) sees logical
// chunk hi.  ds_read_b128 lands 2-way bank-aliased only (free, m136).

// ============ 256x256 core: acc[8][4], 2 phases/K-tile (32 MFMA each) ============
__device__ __forceinline__ void gemm256(
    const u16* __restrict__ A, int lda,
    const u16* __restrict__ B, int ldb,
    int nt, u16* lds, f32x4 acc[8][4])
{
  const int tid  = threadIdx.x;
  const int lane = tid & 63;
  const int wid  = tid >> 6;
  const int wm   = (wid >> 2) * 128;
  const int wn   = (wid & 3) * 64;
  const int lrow = lane & 15;
  const int hi   = lane >> 4;
  u16* dA = lds;
  u16* dB = lds + 4 * HALF2;

  int aoff[8], boff[4];
  #pragma unroll
  for (int mi = 0; mi < 8; ++mi) {
    int r = wm + mi * 16 + lrow;
    aoff[mi] = r * 32 + ((hi ^ ((r >> 1) & 3)) << 3);
  }
  #pragma unroll
  for (int ni = 0; ni < 4; ++ni) {
    int r = wn + ni * 16 + lrow;
    boff[ni] = r * 32 + ((hi ^ ((r >> 1) & 3)) << 3);
  }

  const int f0 = tid, f1 = 512 + tid;
  const int r0 = f0 >> 2, r1 = f1 >> 2;
  const int c0 = (((f0 & 3) ^ ((r0 >> 1) & 3)) << 3);
  const int c1 = (((f1 & 3) ^ ((r1 >> 1) & 3)) << 3);
  const u16* pA0 = A + (size_t)r0 * lda + c0;
  const u16* pA1 = A + (size_t)r1 * lda + c1;
  const u16* pB0 = B + (size_t)r0 * ldb + c0;
  const u16* pB1 = B + (size_t)r1 * ldb + c1;
  const int d0 = f0 * 8, d1 = f1 * 8;

  gload16(pA0,      dA + d0);         gload16(pA1,      dA + d1);
  gload16(pB0,      dB + d0);         gload16(pB1,      dB + d1);
  gload16(pA0 + 32, dA + HALF2 + d0); gload16(pA1 + 32, dA + HALF2 + d1);
  gload16(pB0 + 32, dB + HALF2 + d0); gload16(pB1 + 32, dB + HALF2 + d1);
  pA0 += BK; pA1 += BK; pB0 += BK; pB1 += BK;
  WAITVM4;
  SBAR;

  for (int t = 0; t < nt; ++t) {
    const int cb = (t & 1) * 2;
    const int nb = ((t + 1) & 1) * 2;
    u16* LA0 = dA + cb * HALF2;  u16* LA1 = LA0 + HALF2;
    u16* LB0 = dB + cb * HALF2;  u16* LB1 = LB0 + HALF2;
    const bool s = (t + 1) < nt;
    bf16x8 av[8], bv[4];

    #pragma unroll
    for (int mi = 0; mi < 8; ++mi) av[mi] = *(const bf16x8*)(LA0 + aoff[mi]);
    #pragma unroll
    for (int ni = 0; ni < 4; ++ni) bv[ni] = *(const bf16x8*)(LB0 + boff[ni]);
    if (s) {
      gload16(pA0, dA + nb * HALF2 + d0); gload16(pA1, dA + nb * HALF2 + d1);
      gload16(pB0, dB + nb * HALF2 + d0); gload16(pB1, dB + nb * HALF2 + d1);
    }
    __builtin_amdgcn_s_setprio(1);
    #pragma unroll
    for (int mi = 0; mi < 8; ++mi)
      #pragma unroll
      for (int ni = 0; ni < 4; ++ni)
        acc[mi][ni] = __builtin_amdgcn_mfma_f32_16x16x32_bf16(av[mi], bv[ni], acc[mi][ni], 0, 0, 0);
    __builtin_amdgcn_s_setprio(0);
    if (s) { WAITVM4; } else { WAITVM0; }
    SBAR;

    #pragma unroll
    for (int mi = 0; mi < 8; ++mi) av[mi] = *(const bf16x8*)(LA1 + aoff[mi]);
    #pragma unroll
    for (int ni = 0; ni < 4; ++ni) bv[ni] = *(const bf16x8*)(LB1 + boff[ni]);
    if (s) {
      gload16(pA0 + 32, dA + nb * HALF2 + HALF2 + d0); gload16(pA1 + 32, dA + nb * HALF2 + HALF2 + d1);
      gload16(pB0 + 32, dB + nb * HALF2 + HALF2 + d0); gload16(pB1 + 32, dB + nb * HALF2 + HALF2 + d1);
      pA0 += BK; pA1 += BK; pB0 += BK; pB1 += BK;
    }
    __builtin_amdgcn_s_setprio(1);
    #pragma unroll
    for (int mi = 0; mi < 8; ++mi)
      #pragma unroll
      for (int ni = 0; ni < 4; ++ni)
        acc[mi][ni] = __builtin_amdgcn_mfma_f32_16x16x32_bf16(av[mi], bv[ni], acc[mi][ni], 0, 0, 0);
    __builtin_amdgcn_s_setprio(0);
    if (s) { WAITVM4; }
    SBAR;
  }
}

// ---------------- fp32 -> bf16 convert (vectorized) ----------------
__global__ __launch_bounds__(256) void k_cvt(const float* __restrict__ in,
                                             u16* __restrict__ out, int n) {
  int i = (blockIdx.x * 256 + threadIdx.x) * 4;
  if (i >= n) return;
  float4 v = *(const float4*)(in + i);
  ushort4 o;
  o.x = f2bf(v.x); o.y = f2bf(v.y); o.z = f2bf(v.z); o.w = f2bf(v.w);
  *(ushort4*)(out + i) = o;
}

// 3 weight matrices in one launch (blockIdx.y selects)
__global__ __launch_bounds__(256) void k_cvtw(const float* __restrict__ w0,
                                              const float* __restrict__ w1,
                                              const float* __restrict__ w2,
                                              u16* __restrict__ out) {
  const float* in = (blockIdx.y == 0) ? w0 : (blockIdx.y == 1) ? w1 : w2;
  u16* o = out + (size_t)blockIdx.y * EMBED * EMBED;
  int i = (blockIdx.x * 256 + threadIdx.x) * 4;
  float4 v = *(const float4*)(in + i);
  ushort4 r;
  r.x = f2bf(v.x); r.y = f2bf(v.y); r.z = f2bf(v.z); r.w = f2bf(v.w);
  *(ushort4*)(o + i) = r;
}

// ---------------- QKV projection: C = X * W^T + b ----------------
__global__ __launch_bounds__(512, 2) void k_qkv(
    const u16* __restrict__ Xb, const u16* __restrict__ Wb,
    const float* __restrict__ bq, const float* __restrict__ bk, const float* __restrict__ bv,
    u16* __restrict__ Q, u16* __restrict__ Ks, u16* __restrict__ V)
{
  __shared__ u16 lds[8 * HALF2];
  const int m0 = blockIdx.x * BM2;
  const int n0 = blockIdx.y * BN2;
  const int z  = blockIdx.z;
  const u16*   W    = Wb + (size_t)z * EMBED * EMBED;
  const float* bias = (z == 0) ? bq : (z == 1) ? bk : bv;
  u16* out          = (z == 0) ? Q  : (z == 1) ? Ks : V;
  const float scale = (z == 1) ? KSCALE : 1.0f;

  f32x4 acc[8][4];
  const f32x4 zz = {0.f,0.f,0.f,0.f};
  #pragma unroll
  for (int i = 0; i < 8; ++i) for (int j = 0; j < 4; ++j) acc[i][j] = zz;
  gemm256(Xb + (size_t)m0 * EMBED, EMBED, W + (size_t)n0 * EMBED, EMBED,
          EMBED / BK, lds, acc);

  const int lane = threadIdx.x & 63, wid = threadIdx.x >> 6;
  const int wm = (wid >> 2) * 128, wn = (wid & 3) * 64;
  const int lrow = lane & 15, hi = lane >> 4;
  #pragma unroll
  for (int mi = 0; mi < 8; ++mi)
    #pragma unroll
    for (int ni = 0; ni < 4; ++ni)
      #pragma unroll
      for (int rr = 0; rr < 4; ++rr) {
        int gm = m0 + wm + mi * 16 + hi * 4 + rr;
        int gn = n0 + wn + ni * 16 + lrow;
        out[(size_t)gm * EMBED + gn] = f2bf((acc[mi][ni][rr] + bias[gn]) * scale);
      }
}

// -- S = Q*K^T, P = exp2(S) masked, D[j] += colsum; XCD-pinned 288-job grid --
// slot s: xcd=s&7, q=s>>3 decodes 36 lower-tri (i,j); b=(xcd-i)&7.
// All (i+1) blocks sharing a Q-panel land on ONE XCD -> Q staging = L2 hits.
__global__ __launch_bounds__(512, 2) void k_spd(
    const u16* __restrict__ Q, const u16* __restrict__ Ks,
    u16* __restrict__ P, float* __restrict__ D)
{
  const int s   = blockIdx.x;
  const int xcd = s & 7;
  const int q   = s >> 3;            // 0..35
  int it = 0;
  while (q >= ((it + 1) * (it + 2)) / 2) ++it;   // i with C(i)<=q<C(i+1), C(i)=i(i+1)/2
  const int jt = q - (it * (it + 1)) / 2;        // 0..it
  const int b  = (xcd - it) & 7;
  const int i0 = it * BM2;
  const int j0 = jt * BN2;

  __shared__ u16 lds[BM2 * PLD];             // 133120 B: gemm uses first 128 KiB
  const u16* A = Q  + (size_t)b * WINDOW * EMBED + (size_t)i0 * EMBED;
  const u16* B = Ks + (size_t)b * WINDOW * EMBED + (size_t)j0 * EMBED;
  f32x4 acc[8][4];
  const f32x4 zz = {0.f,0.f,0.f,0.f};
  #pragma unroll
  for (int i = 0; i < 8; ++i) for (int j = 0; j < 4; ++j) acc[i][j] = zz;
  gemm256(A, EMBED, B, EMBED, EMBED / BK, lds, acc);

  u16* Pb   = P + (size_t)b * WINDOW * WINDOW;
  float* Db = D + (size_t)b * WINDOW;
  const int tid  = threadIdx.x;
  const int lane = tid & 63, wid = tid >> 6;
  const int wm = (wid >> 2) * 128, wn = (wid & 3) * 64;
  const int lrow = lane & 15, hi = lane >> 4;

  // phase 1: P-tile -> LDS [256][PLD]; column sums -> atomics
  #pragma unroll
  for (int ni = 0; ni < 4; ++ni) {
    int lj = wn + ni * 16 + lrow;
    float csum = 0.f;
    #pragma unroll
    for (int mi = 0; mi < 8; ++mi)
      #pragma unroll
      for (int rr = 0; rr < 4; ++rr) {
        int li = wm + mi * 16 + hi * 4 + rr;
        float p = ((i0 + li) >= (j0 + lj)) ? exp2f(acc[mi][ni][rr]) : 0.0f;
        lds[li * PLD + lj] = f2bf(p);
        csum += p;
      }
    csum += __shfl_xor(csum, 16, 64);
    csum += __shfl_xor(csum, 32, 64);
    if (hi == 0) atomicAdd(&Db[j0 + lj], csum);
  }
  __syncthreads();

  // phase 2: coalesced copy-out (2 rows per wave-instruction)
  #pragma unroll
  for (int it2 = 0; it2 < 16; ++it2) {
    int f   = it2 * 512 + tid;
    int row = f >> 5;
    int c   = f & 31;
    bf16x8 v = *(const bf16x8*)(lds + row * PLD + c * 8);
    *(bf16x8*)(Pb + (size_t)(i0 + row) * WINDOW + j0 + c * 8) = v;
  }
}

// ---------------- Vdt[e][j] = V[j][e] / D[j]  (transpose + scale) ----------------
__global__ __launch_bounds__(256) void k_vdt(
    const u16* __restrict__ V, const float* __restrict__ D, u16* __restrict__ Vdt)
{
  __shared__ u16 tile[64][68];
  const int j0 = blockIdx.x * 64, e0 = blockIdx.y * 64, b = blockIdx.z;
  const u16* Vb = V   + (size_t)b * WINDOW * EMBED;
  u16* Tb       = Vdt + (size_t)b * EMBED * WINDOW;
  const float* Db = D + (size_t)b * WINDOW;
  const int t = threadIdx.x;
  const int rr = t >> 4;
  const int cc = (t & 15) * 4;
  #pragma unroll
  for (int p = 0; p < 4; ++p) {
    int r = p * 16 + rr;
    *(uint2*)&tile[r][cc] = *(const uint2*)(Vb + (size_t)(j0 + r) * EMBED + e0 + cc);
  }
  __syncthreads();
  #pragma unroll
  for (int p = 0; p < 4; ++p) {
    int er = p * 16 + rr;
    ushort4 o;
    o.x = f2bf(bf2f(tile[cc + 0][er]) / Db[j0 + cc + 0]);
    o.y = f2bf(bf2f(tile[cc + 1][er]) / Db[j0 + cc + 1]);
    o.z = f2bf(bf2f(tile[cc + 2][er]) / Db[j0 + cc + 2]);
    o.w = f2bf(bf2f(tile[cc + 3][er]) / Db[j0 + cc + 3]);
    *(ushort4*)(Tb + (size_t)(e0 + er) * WINDOW + j0 + cc) = o;
  }
}

// ---- O = P * Vdt^T (causal K-length), XCD-pinned 256-job grid, LPT ----
// slot s: xcd=s&7, q=s>>3 (0..31): e=q&3, i=7-(q>>2), b=(xcd-i)&7.
// The 4 e-blocks sharing a P-panel co-reside on one XCD -> P reads = L2 hits.
__global__ __launch_bounds__(512, 2) void k_out(
    const u16* __restrict__ P, const u16* __restrict__ Vdt, float* __restrict__ O)
{
  __shared__ u16 lds[8 * HALF2];
  const int s   = blockIdx.x;
  const int xcd = s & 7;
  const int q   = s >> 3;            // 0..31
  const int et  = q & 3;
  const int it  = 7 - (q >> 2);      // longest first per XCD
  const int b   = (xcd - it) & 7;
  const int i0  = it * BM2;
  const int e0  = et * BN2;

  const u16* A = P   + (size_t)b * WINDOW * WINDOW + (size_t)i0 * WINDOW;
  const u16* B = Vdt + (size_t)b * EMBED * WINDOW  + (size_t)e0 * WINDOW;
  f32x4 acc[8][4];
  const f32x4 zz = {0.f,0.f,0.f,0.f};
  #pragma unroll
  for (int i = 0; i < 8; ++i) for (int j = 0; j < 4; ++j) acc[i][j] = zz;
  gemm256(A, WINDOW, B, WINDOW, (i0 + BM2) / BK, lds, acc);  // j <= i only

  float* Ob = O + (size_t)b * WINDOW * EMBED;
  const int lane = threadIdx.x & 63, wid = threadIdx.x >> 6;
  const int wm = (wid >> 2) * 128, wn = (wid & 3) * 64;
  const int lrow = lane & 15, hi = lane >> 4;
  #pragma unroll
  for (int mi = 0; mi < 8; ++mi)
    #pragma unroll
    for (int ni = 0; ni < 4; ++ni)
      #pragma unroll
      for (int rr = 0; rr < 4; ++rr) {
        int gi = i0 + wm + mi * 16 + hi * 4 + rr;
        int ge = e0 + wn + ni * 16 + lrow;
        Ob[(size_t)gi * EMBED + ge] = acc[mi][ni][rr];
      }
}

extern "C" void kernel_launch(void* const* d_in, const int* in_sizes, int n_in,
                              void* d_out, int out_size, void* d_ws, size_t ws_size,
                              hipStream_t stream) {
  const float* X  = (const float*)d_in[0];
  const float* Wq = (const float*)d_in[1];
  const float* bq = (const float*)d_in[2];
  const float* Wk = (const float*)d_in[3];
  const float* bk = (const float*)d_in[4];
  const float* Wv = (const float*)d_in[5];
  const float* bv = (const float*)d_in[6];
  float* O = (float*)d_out;

  char* ws = (char*)d_ws;
  size_t off = 0;
  auto alloc = [&](size_t bytes) -> void* {
    void* p = ws + off; off += (bytes + 255) & ~(size_t)255; return p;
  };
  u16*  Xb  = (u16*)alloc((size_t)MTOT * EMBED * 2);
  u16*  Wb  = (u16*)alloc((size_t)3 * EMBED * EMBED * 2);
  u16*  Qb  = (u16*)alloc((size_t)MTOT * EMBED * 2);
  u16*  Kb  = (u16*)alloc((size_t)MTOT * EMBED * 2);          // pre-scaled by log2e/32
  u16*  Vb  = (u16*)alloc((size_t)MTOT * EMBED * 2);
  u16*  Vdt = (u16*)alloc((size_t)BATCH * EMBED * WINDOW * 2);
  u16*  P   = (u16*)alloc((size_t)BATCH * WINDOW * WINDOW * 2);
  float* D  = (float*)alloc((size_t)MTOT * 4);
  (void)ws_size; (void)in_sizes; (void)n_in; (void)out_size;

  // 0) fp32 -> bf16 converts (X; then all 3 W's in one launch)
  k_cvt<<<dim3((MTOT * EMBED / 4 + 255) / 256), 256, 0, stream>>>(X, Xb, MTOT * EMBED);
  k_cvtw<<<dim3(EMBED * EMBED / 4 / 256, 3), 256, 0, stream>>>(Wq, Wk, Wv, Wb);

  // 1) Q/K/V projections (768 blocks = 3 dispatch rounds)
  k_qkv<<<dim3(MTOT / BM2, EMBED / BN2, 3), 512, 0, stream>>>(Xb, Wb, bq, bk, bv, Qb, Kb, Vb);

  // 2) P = exp(QK^T/sqrt(E)) masked; D[j] = column sums (288 XCD-pinned jobs)
  (void)hipMemsetAsync(D, 0, (size_t)MTOT * 4, stream);
  k_spd<<<dim3(288), 512, 0, stream>>>(Qb, Kb, P, D);

  // 3) Vdt[e][j] = V[j][e] / D[j]
  k_vdt<<<dim3(WINDOW / 64, EMBED / 64, BATCH), 256, 0, stream>>>(Vb, D, Vdt);

  // 4) O = P * Vdt^T (256 XCD-pinned jobs, longest-first per XCD)
  k_out<<<dim3(256), 512, 0, stream>>>(P, Vdt, O);
}